// Round 5
// baseline (53.368 us; speedup 1.0000x reference)
//
#include <hip/hip_runtime.h>
#include <stdint.h>

// ---------------- problem constants ----------------
#define B_ROWS 16384
#define LATD   128
#define HIDD   1024

typedef __bf16 bf16x8 __attribute__((ext_vector_type(8)));
typedef float  f32x4  __attribute__((ext_vector_type(4)));
typedef float  f32x4v __attribute__((ext_vector_type(4)));
typedef unsigned short ushort8v __attribute__((ext_vector_type(8)));
typedef unsigned int   uint2v   __attribute__((ext_vector_type(2)));

// ---------------- threefry2x32 (matches JAX, partitionable default) ----------------
struct TF2 { unsigned int a, b; };

#define TF_R(x0,x1,r) { x0 += x1; x1 = ((x1 << (r)) | (x1 >> (32 - (r)))); x1 ^= x0; }

__host__ __device__ constexpr TF2 threefry2x32(unsigned k0, unsigned k1, unsigned c0, unsigned c1) {
  unsigned ks2 = k0 ^ k1 ^ 0x1BD11BDAu;
  unsigned x0 = c0 + k0, x1 = c1 + k1;
  TF_R(x0,x1,13) TF_R(x0,x1,15) TF_R(x0,x1,26) TF_R(x0,x1,6)
  x0 += k1;  x1 += ks2 + 1u;
  TF_R(x0,x1,17) TF_R(x0,x1,29) TF_R(x0,x1,16) TF_R(x0,x1,24)
  x0 += ks2; x1 += k0 + 2u;
  TF_R(x0,x1,13) TF_R(x0,x1,15) TF_R(x0,x1,26) TF_R(x0,x1,6)
  x0 += k0;  x1 += k1 + 3u;
  TF_R(x0,x1,17) TF_R(x0,x1,29) TF_R(x0,x1,16) TF_R(x0,x1,24)
  x0 += k1;  x1 += ks2 + 4u;
  TF_R(x0,x1,13) TF_R(x0,x1,15) TF_R(x0,x1,26) TF_R(x0,x1,6)
  x0 += ks2; x1 += k0 + 5u;
  return {x0, x1};
}

constexpr TF2 NK0 = threefry2x32(0u, 1u, 0u, 0u);  // bin heads
constexpr TF2 NK1 = threefry2x32(0u, 1u, 0u, 1u);  // like heads
constexpr TF2 NK2 = threefry2x32(0u, 1u, 0u, 2u);  // mask heads

__device__ __forceinline__ unsigned short f2bf(float f) {
  unsigned u = __float_as_uint(f);
  return (unsigned short)((u + 0x7fffu + ((u >> 16) & 1u)) >> 16);
}

// ---------------- prep: fragment-linear packed bf16 weights in d_ws ----------------
// W1p frag f = nt*4+ks: elem (lane l, j): n = (f>>2)*16 + (l&15); k = (f&3)*32 + (l>>4)*8 + j
// Wallp frag g = nt*32+kt: same intra-frag mapping
__global__ void prep_kernel(const float* __restrict__ W1,
                            const float* __restrict__ Wnum, const float* __restrict__ Wcat,
                            const float* __restrict__ Wbin, const float* __restrict__ Wlike,
                            const float* __restrict__ Wmask,
                            const float* __restrict__ bnum, const float* __restrict__ bcat,
                            const float* __restrict__ bbin, const float* __restrict__ blike,
                            const float* __restrict__ bmask,
                            unsigned short* __restrict__ W1p,
                            unsigned short* __restrict__ Wallp,
                            float* __restrict__ ball) {
  int t = blockIdx.x * 256 + threadIdx.x;
  if (t < 16384) {
    int f = t >> 6, l = t & 63;
    int n = (f >> 2) * 16 + (l & 15);
    int kk0 = (f & 3) * 32 + (l >> 4) * 8;
    ushort8v p;
    #pragma unroll
    for (int j = 0; j < 8; ++j) p[j] = f2bf(W1[(size_t)(kk0 + j) * HIDD + n]);
    *(ushort8v*)(W1p + (size_t)t * 8) = p;
  } else if (t < 16384 + 40960) {
    int t2 = t - 16384;
    int g = t2 >> 6, l = t2 & 63;
    int nt = g >> 5, kt = g & 31;
    int n = nt * 16 + (l & 15);
    int kk0 = kt * 32 + (l >> 4) * 8;
    ushort8v p;
    #pragma unroll
    for (int j = 0; j < 8; ++j) {
      int kk = kk0 + j;
      float v = 0.f;
      if (n < 32)       v = Wnum [(size_t)kk * 32  + n];
      else if (n < 230) v = Wcat [(size_t)kk * 198 + (n - 32)];
      else if (n < 238) v = Wbin [(size_t)kk * 8   + (n - 230)];
      else if (n < 240) v = Wlike[(size_t)kk * 2   + (n - 238)];
      else if (n < 294) v = Wmask[(size_t)kk * 54  + (n - 240)];
      p[j] = f2bf(v);
    }
    *(ushort8v*)(Wallp + (size_t)t2 * 8) = p;
  } else if (t < 16384 + 40960 + 320) {
    int n = t - (16384 + 40960);
    float v = 0.f;
    if (n < 32)       v = bnum [n];
    else if (n < 230) v = bcat [n - 32];
    else if (n < 238) v = bbin [n - 230];
    else if (n < 240) v = blike[n - 238];
    else if (n < 294) v = bmask[n - 240];
    ball[n] = v;
  }
}

// ---------------- kernel A: h = relu(z@W1 + b1), fragment-tiled bf16 to d_ws ----------------
// h layout: tile(rowblk 0..255, chunk 0..7) = 16 KB; within tile, element (r_loc, hcl):
//   byte = ((hcl>>5)*4 + (r_loc>>4))*1024 + (r_loc&15)*16 + ((hcl>>3)&3)*256 + (hcl&7)*2
// i.e. B-frag-linear: frag (rt,ks) at (ks*4+rt)*1024, lane-linear 16 B — zero-conflict ds_read_b128.
// Swapped MFMA (A=W1^T, B=z) so each lane owns 4 consecutive hc per acc reg.
// 1024 WGs x 256 thr (4 waves), wave = 32 rows x 128 hc. No LDS, no barriers.
__global__ __launch_bounds__(256, 4) void h_kernel(
    const float* __restrict__ z, const float* __restrict__ b1,
    const unsigned short* __restrict__ W1p, unsigned char* __restrict__ hws) {
  const int tid = threadIdx.x;
  const int lane = tid & 63;
  const int w    = tid >> 6;
  const int l15  = lane & 15;
  const int l4   = lane >> 4;
  const int g    = blockIdx.x;
  const int rb   = (g >> 1) * 32;           // 32-row block
  const int hcb  = (g & 1) * 512 + w * 128; // 128-hc slice for this wave

  // z B-frags: B[k][n]=z[row n][k]; lane: n-local=l15, k=ks*32+l4*8+j
  bf16x8 zb[2][4];
  #pragma unroll
  for (int rt = 0; rt < 2; ++rt)
    #pragma unroll
    for (int ks = 0; ks < 4; ++ks) {
      const float* src = z + (size_t)(rb + rt * 16 + l15) * LATD + ks * 32 + l4 * 8;
      f32x4 f0 = *(const f32x4*)src;
      f32x4 f1 = *(const f32x4*)(src + 4);
      bf16x8 p;
      p[0] = (__bf16)f0[0]; p[1] = (__bf16)f0[1]; p[2] = (__bf16)f0[2]; p[3] = (__bf16)f0[3];
      p[4] = (__bf16)f1[0]; p[5] = (__bf16)f1[1]; p[6] = (__bf16)f1[2]; p[7] = (__bf16)f1[3];
      zb[rt][ks] = p;
    }

  f32x4 acc[8][2] = {};
  #pragma unroll
  for (int t = 0; t < 8; ++t) {
    #pragma unroll
    for (int ks = 0; ks < 4; ++ks) {
      bf16x8 wA = *(const bf16x8*)(W1p + ((size_t)((hcb >> 4) + t) * 4 + ks) * 512 + lane * 8);
      #pragma unroll
      for (int rt = 0; rt < 2; ++rt)
        acc[t][rt] = __builtin_amdgcn_mfma_f32_16x16x32_bf16(wA, zb[rt][ks], acc[t][rt], 0, 0, 0);
    }
  }

  // epilogue: +bias, relu, pack quads, store to fragment-linear tile
  const size_t tile_base = ((size_t)(rb >> 6) * 8 + (hcb >> 7)) * 16384;
  const int rhalf_base = (rb & 32) >> 4;
  #pragma unroll
  for (int t = 0; t < 8; ++t) {
    f32x4 bias = *(const f32x4*)(b1 + hcb + t * 16 + l4 * 4);
    #pragma unroll
    for (int rt = 0; rt < 2; ++rt) {
      // D (swapped): col=l15 -> z-row local, row=l4*4+j -> hc local
      float v0 = fmaxf(acc[t][rt][0] + bias[0], 0.f);
      float v1 = fmaxf(acc[t][rt][1] + bias[1], 0.f);
      float v2 = fmaxf(acc[t][rt][2] + bias[2], 0.f);
      float v3 = fmaxf(acc[t][rt][3] + bias[3], 0.f);
      uint2v u;
      u[0] = (unsigned)f2bf(v0) | ((unsigned)f2bf(v1) << 16);
      u[1] = (unsigned)f2bf(v2) | ((unsigned)f2bf(v3) << 16);
      int rhalf = rhalf_base + rt;                  // r_loc>>4
      int byte = (((t >> 1) * 4 + rhalf) * 1024)    // frag (ks=t>>1, rt=rhalf)
               + l15 * 16
               + (((t & 1) * 2 + (l4 >> 1)) * 256)  // (hcl>>3)&3
               + ((l4 & 1) * 8);                    // quad half
      *(uint2v*)(hws + tile_base + byte) = u;
    }
  }
}

// ---------------- kernel B: out = h @ Wall + bias, gumbel heads, scatter ----------------
// 256 WGs x 640 thr (10 waves). Wave = 64 rows x 32 out cols, full K=1024 (no reduction).
// h chunks staged LDS via global_load_lds, double-buffered, 1 __syncthreads/chunk,
// stage(c+1) issued a full chunk before its use. Fragment-linear -> lane-linear ds_read_b128.
__global__ __launch_bounds__(640, 2) void out_kernel(
    const unsigned char* __restrict__ hws, const unsigned short* __restrict__ Wallp,
    const float* __restrict__ ball, float* __restrict__ out) {
  __shared__ __align__(16) unsigned char smem[114944];  // buf0 16K | buf1 16K | outs 64x321 f32
  float* outs = (float*)(smem + 32768);

  const int tid  = threadIdx.x;
  const int lane = tid & 63;
  const int wv   = tid >> 6;        // 0..9
  const int l15  = lane & 15;
  const int l4   = lane >> 4;
  const int rb   = blockIdx.x * 64;
  const int cb   = wv * 32;
  const size_t hblk = (size_t)blockIdx.x * 8 * 16384;

  const int s0 = (wv < 6) ? wv * 2 : 12 + (wv - 6);
  const int ns = (wv < 6) ? 2 : 1;

  f32x4 acc[4][2] = {};

  // stage chunk 0
  for (int i = 0; i < ns; ++i) {
    int s = s0 + i;
    const unsigned char* src = hws + hblk + (size_t)s * 1024 + lane * 16;
    __builtin_amdgcn_global_load_lds(
        (const __attribute__((address_space(1))) unsigned int*)src,
        (__attribute__((address_space(3))) unsigned int*)(smem + s * 1024), 16, 0, 0);
  }

  for (int c = 0; c < 8; ++c) {
    __syncthreads();   // stage(c) resident (issued a full chunk ago); drains all vmcnt
    if (c < 7) {
      unsigned char* dbuf = smem + ((c + 1) & 1) * 16384;
      for (int i = 0; i < ns; ++i) {
        int s = s0 + i;
        const unsigned char* src = hws + hblk + (size_t)(c + 1) * 16384 + s * 1024 + lane * 16;
        __builtin_amdgcn_global_load_lds(
            (const __attribute__((address_space(1))) unsigned int*)src,
            (__attribute__((address_space(3))) unsigned int*)(dbuf + s * 1024), 16, 0, 0);
      }
    }
    // weights for this chunk (L2 stream; latency hides under ds_reads/MFMA)
    bf16x8 wb[2][4];
    #pragma unroll
    for (int ct = 0; ct < 2; ++ct)
      #pragma unroll
      for (int ks = 0; ks < 4; ++ks)
        wb[ct][ks] = *(const bf16x8*)(Wallp +
            ((size_t)(((cb >> 4) + ct) * 32 + c * 4 + ks) * 64 + lane) * 8);
    const unsigned char* buf = smem + (c & 1) * 16384;
    #pragma unroll
    for (int ks = 0; ks < 4; ++ks) {
      bf16x8 ha[4];
      #pragma unroll
      for (int rt = 0; rt < 4; ++rt)
        ha[rt] = *(const bf16x8*)(buf + (ks * 4 + rt) * 1024 + lane * 16);
      #pragma unroll
      for (int rt = 0; rt < 4; ++rt)
        #pragma unroll
        for (int ct = 0; ct < 2; ++ct)
          acc[rt][ct] = __builtin_amdgcn_mfma_f32_16x16x32_bf16(ha[rt], wb[ct][ks], acc[rt][ct], 0, 0, 0);
    }
  }

  // ---- acc -> outs[64][321] (+fused bias); each wave owns its 32 cols ----
  float bias2[2];
  #pragma unroll
  for (int ct = 0; ct < 2; ++ct) bias2[ct] = ball[cb + ct * 16 + l15];
  #pragma unroll
  for (int rt = 0; rt < 4; ++rt)
    #pragma unroll
    for (int ct = 0; ct < 2; ++ct)
      #pragma unroll
      for (int j = 0; j < 4; ++j)
        outs[(rt * 16 + l4 * 4 + j) * 321 + cb + ct * 16 + l15] = acc[rt][ct][j] + bias2[ct];
  __syncthreads();

  // ---- write num + cat blocks (row-major [B, card] chunks, contiguous float4) ----
  {
    constexpr int cards[13] = {32,10,20,15,8,30,12,5,25,6,40,18,9};
    constexpr int cbase[13] = {0,32,42,62,77,85,115,127,132,157,163,203,221};
    #pragma unroll
    for (int blk = 0; blk < 13; ++blk) {
      const int card = cards[blk];
      const int cbs  = cbase[blk];
      float* gout = out + (size_t)B_ROWS * cbs + (size_t)rb * card;
      for (int v = tid; v < card * 16; v += 640) {
        int gg = v * 4;
        f32x4v vbuf;
        #pragma unroll
        for (int e = 0; e < 4; ++e) {
          int ge = gg + e;
          int brow = ge / card;
          int j = ge - brow * card;
          vbuf[e] = outs[brow * 321 + cbs + j];
        }
        *(f32x4v*)(gout + gg) = vbuf;
      }
    }
  }

  // ---- gumbel-sigmoid heads: cols 230..293, out[B*c + b] ----
  if (tid < 512) {
    int c = 230 + (tid >> 3);
    unsigned ka, kb; int Nh, head;
    if (c < 238)      { ka = NK0.a; kb = NK0.b; Nh = 8;  head = c - 230; }
    else if (c < 240) { ka = NK1.a; kb = NK1.b; Nh = 2;  head = c - 238; }
    else              { ka = NK2.a; kb = NK2.b; Nh = 54; head = c - 240; }
    #pragma unroll
    for (int q = 0; q < 2; ++q) {
      int rq = (tid & 7) * 4 + q * 32;
      f32x4v vbuf;
      #pragma unroll
      for (int e = 0; e < 4; ++e) {
        int rl = rq + e;
        float x = outs[rl * 321 + c];
        unsigned j = (unsigned)((rb + rl) * Nh + head);
        TF2 t = threefry2x32(ka, kb, 0u, j);
        unsigned bits = t.a ^ t.b;
        float u  = __uint_as_float((bits >> 9) | 0x3f800000u) - 1.0f;
        float gn = -logf(-logf(u + 1e-20f) + 1e-20f);
        vbuf[e] = 1.0f / (1.0f + expf(-(x + gn)));
      }
      *(f32x4v*)(out + (size_t)B_ROWS * c + rb + rq) = vbuf;
    }
  }
}

// ---------------- fallback fused decoder (round-2, proven 34 us) ----------------
__global__ __launch_bounds__(512, 2) void decoder_kernel(
    const float* __restrict__ z, const float* __restrict__ b1,
    const unsigned short* __restrict__ W1p, const unsigned short* __restrict__ Wallp,
    const float* __restrict__ ball, float* __restrict__ out) {
  __shared__ __align__(16) unsigned char smem[82176];
  unsigned short* zs  = (unsigned short*)smem;
  unsigned short* hs0 = (unsigned short*)(smem + 17408);
  unsigned short* hs1 = (unsigned short*)(smem + 34816);
  float* outs = (float*)smem;

  const int tid  = threadIdx.x;
  const int lane = tid & 63;
  const int wv   = tid >> 6;
  const int wc   = wv & 3;
  const int wk   = wv >> 2;
  const int l15  = lane & 15;
  const int l4   = lane >> 4;
  const int r0   = blockIdx.x * 64;

  #pragma unroll
  for (int it = 0; it < 2; ++it) {
    int ch  = tid + it * 512;
    int row = ch >> 4;
    int k0  = (ch & 15) * 8;
    const float* src = z + (size_t)(r0 + row) * LATD + k0;
    f32x4 f0 = *(const f32x4*)src;
    f32x4 f1 = *(const f32x4*)(src + 4);
    ushort8v p;
    p[0] = f2bf(f0[0]); p[1] = f2bf(f0[1]); p[2] = f2bf(f0[2]); p[3] = f2bf(f0[3]);
    p[4] = f2bf(f1[0]); p[5] = f2bf(f1[1]); p[6] = f2bf(f1[2]); p[7] = f2bf(f1[3]);
    *(ushort8v*)(zs + row * 136 + k0) = p;
  }

  float bb[4][2];
  #pragma unroll
  for (int i = 0; i < 4; ++i)
    #pragma unroll
    for (int ct = 0; ct < 2; ++ct)
      bb[i][ct] = b1[(wk * 4 + i) * 128 + wc * 32 + ct * 16 + l15];
  float bias2[5];
  #pragma unroll
  for (int ct = 0; ct < 5; ++ct) bias2[ct] = ball[wc * 80 + ct * 16 + l15];

  unsigned short* hw = wk ? hs1 : hs0;
  f32x4 acc2[4][5] = {};
  __syncthreads();

  #pragma unroll
  for (int i = 0; i < 4; ++i) {
    const int c = wk * 4 + i;
    bf16x8 wb1[2][4];
    #pragma unroll
    for (int ct = 0; ct < 2; ++ct)
      #pragma unroll
      for (int ks = 0; ks < 4; ++ks)
        wb1[ct][ks] = *(const bf16x8*)(W1p + (size_t)(((c * 8 + wc * 2 + ct) * 4 + ks) * 64 + lane) * 8);
    f32x4 acc1[4][2] = {};
    #pragma unroll
    for (int ks = 0; ks < 4; ++ks) {
      bf16x8 za[4];
      #pragma unroll
      for (int rt = 0; rt < 4; ++rt)
        za[rt] = *(const bf16x8*)(zs + (rt * 16 + l15) * 136 + ks * 32 + l4 * 8);
      #pragma unroll
      for (int rt = 0; rt < 4; ++rt)
        #pragma unroll
        for (int ct = 0; ct < 2; ++ct)
          acc1[rt][ct] = __builtin_amdgcn_mfma_f32_16x16x32_bf16(za[rt], wb1[ct][ks], acc1[rt][ct], 0, 0, 0);
    }
    bf16x8 wb2[5][4];
    #pragma unroll
    for (int ct = 0; ct < 5; ++ct)
      #pragma unroll
      for (int ks = 0; ks < 4; ++ks)
        wb2[ct][ks] = *(const bf16x8*)(Wallp + (size_t)(((wc * 5 + ct) * 32 + c * 4 + ks) * 64 + lane) * 8);
    __syncthreads();
    #pragma unroll
    for (int rt = 0; rt < 4; ++rt)
      #pragma unroll
      for (int ct = 0; ct < 2; ++ct)
        #pragma unroll
        for (int j = 0; j < 4; ++j) {
          float v = fmaxf(acc1[rt][ct][j] + bb[i][ct], 0.f);
          hw[(rt * 16 + l4 * 4 + j) * 136 + wc * 32 + ct * 16 + l15] = f2bf(v);
        }
    __syncthreads();
    #pragma unroll
    for (int ks = 0; ks < 4; ++ks) {
      bf16x8 ha[4];
      #pragma unroll
      for (int rt = 0; rt < 4; ++rt)
        ha[rt] = *(const bf16x8*)(hw + (rt * 16 + l15) * 136 + ks * 32 + l4 * 8);
      #pragma unroll
      for (int rt = 0; rt < 4; ++rt)
        #pragma unroll
        for (int ct = 0; ct < 5; ++ct)
          acc2[rt][ct] = __builtin_amdgcn_mfma_f32_16x16x32_bf16(ha[rt], wb2[ct][ks], acc2[rt][ct], 0, 0, 0);
    }
  }
  __syncthreads();

  if (wk == 0) {
    #pragma unroll
    for (int rt = 0; rt < 4; ++rt)
      #pragma unroll
      for (int ct = 0; ct < 5; ++ct)
        #pragma unroll
        for (int j = 0; j < 4; ++j)
          outs[(rt * 16 + l4 * 4 + j) * 321 + wc * 80 + ct * 16 + l15] = acc2[rt][ct][j] + bias2[ct];
  }
  __syncthreads();
  if (wk == 1) {
    #pragma unroll
    for (int rt = 0; rt < 4; ++rt)
      #pragma unroll
      for (int ct = 0; ct < 5; ++ct)
        #pragma unroll
        for (int j = 0; j < 4; ++j)
          outs[(rt * 16 + l4 * 4 + j) * 321 + wc * 80 + ct * 16 + l15] += acc2[rt][ct][j];
  }
  __syncthreads();

  {
    constexpr int cards[13] = {32,10,20,15,8,30,12,5,25,6,40,18,9};
    constexpr int cbase[13] = {0,32,42,62,77,85,115,127,132,157,163,203,221};
    #pragma unroll
    for (int blk = 0; blk < 13; ++blk) {
      const int card = cards[blk];
      const int cbs  = cbase[blk];
      float* gout = out + (size_t)B_ROWS * cbs + (size_t)r0 * card;
      for (int v = tid; v < card * 16; v += 512) {
        int gg = v * 4;
        f32x4v vbuf;
        #pragma unroll
        for (int e = 0; e < 4; ++e) {
          int ge = gg + e;
          int brow = ge / card;
          int j = ge - brow * card;
          vbuf[e] = outs[brow * 321 + cbs + j];
        }
        *(f32x4v*)(gout + gg) = vbuf;
      }
    }
  }
  {
    int c = 230 + (tid >> 3);
    unsigned ka, kb; int Nh, head;
    if (c < 238)      { ka = NK0.a; kb = NK0.b; Nh = 8;  head = c - 230; }
    else if (c < 240) { ka = NK1.a; kb = NK1.b; Nh = 2;  head = c - 238; }
    else              { ka = NK2.a; kb = NK2.b; Nh = 54; head = c - 240; }
    #pragma unroll
    for (int q = 0; q < 2; ++q) {
      int rq = (tid & 7) * 4 + q * 32;
      f32x4v vbuf;
      #pragma unroll
      for (int e = 0; e < 4; ++e) {
        int rl = rq + e;
        float x = outs[rl * 321 + c];
        unsigned j = (unsigned)((r0 + rl) * Nh + head);
        TF2 t = threefry2x32(ka, kb, 0u, j);
        unsigned bits = t.a ^ t.b;
        float u  = __uint_as_float((bits >> 9) | 0x3f800000u) - 1.0f;
        float gn = -logf(-logf(u + 1e-20f) + 1e-20f);
        vbuf[e] = 1.0f / (1.0f + expf(-(x + gn)));
      }
      *(f32x4v*)(out + (size_t)B_ROWS * c + r0 + rq) = vbuf;
    }
  }
}

// ---------------- launch ----------------
extern "C" void kernel_launch(void* const* d_in, const int* in_sizes, int n_in,
                              void* d_out, int out_size, void* d_ws, size_t ws_size,
                              hipStream_t stream) {
  const float* z     = (const float*)d_in[0];
  const float* W1    = (const float*)d_in[1];
  const float* b1    = (const float*)d_in[2];
  const float* Wnum  = (const float*)d_in[3];
  const float* bnum  = (const float*)d_in[4];
  const float* Wcat  = (const float*)d_in[5];
  const float* bcat  = (const float*)d_in[6];
  const float* Wbin  = (const float*)d_in[7];
  const float* bbin  = (const float*)d_in[8];
  const float* Wlike = (const float*)d_in[9];
  const float* blike = (const float*)d_in[10];
  const float* Wmask = (const float*)d_in[11];
  const float* bmask = (const float*)d_in[12];

  unsigned short* W1p   = (unsigned short*)d_ws;            // 131072 bf16 = 256 KB
  unsigned short* Wallp = W1p + 131072;                     // 327680 bf16 = 640 KB
  float*          ball  = (float*)(Wallp + 327680);         // 320 f32
  const size_t HOFF = 1u << 20;                             // h at +1 MB
  unsigned char*  hws   = (unsigned char*)d_ws + HOFF;      // 32 MB fragment-tiled h

  const int total = 16384 + 40960 + 320;
  prep_kernel<<<(total + 255) / 256, 256, 0, stream>>>(
      W1, Wnum, Wcat, Wbin, Wlike, Wmask, bnum, bcat, bbin, blike, bmask,
      W1p, Wallp, ball);

  if (ws_size >= HOFF + (size_t)32 * 1024 * 1024) {
    h_kernel<<<1024, 256, 0, stream>>>(z, b1, W1p, hws);
    out_kernel<<<256, 640, 0, stream>>>(hws, Wallp, ball, (float*)d_out);
  } else {
    decoder_kernel<<<B_ROWS / 64, 512, 0, stream>>>(
        z, b1, W1p, Wallp, ball, (float*)d_out);
  }
}

// Round 6
// 49.148 us; speedup vs baseline: 1.0859x; 1.0859x over previous
//
#include <hip/hip_runtime.h>
#include <stdint.h>

// ---------------- problem constants ----------------
#define B_ROWS 16384
#define LATD   128
#define HIDD   1024

typedef __bf16 bf16x8 __attribute__((ext_vector_type(8)));
typedef float  f32x4  __attribute__((ext_vector_type(4)));
typedef float  f32x4v __attribute__((ext_vector_type(4)));
typedef unsigned short ushort8v __attribute__((ext_vector_type(8)));
typedef unsigned int   uint2v   __attribute__((ext_vector_type(2)));

// ---------------- threefry2x32 (matches JAX, partitionable default) ----------------
struct TF2 { unsigned int a, b; };

#define TF_R(x0,x1,r) { x0 += x1; x1 = ((x1 << (r)) | (x1 >> (32 - (r)))); x1 ^= x0; }

__host__ __device__ constexpr TF2 threefry2x32(unsigned k0, unsigned k1, unsigned c0, unsigned c1) {
  unsigned ks2 = k0 ^ k1 ^ 0x1BD11BDAu;
  unsigned x0 = c0 + k0, x1 = c1 + k1;
  TF_R(x0,x1,13) TF_R(x0,x1,15) TF_R(x0,x1,26) TF_R(x0,x1,6)
  x0 += k1;  x1 += ks2 + 1u;
  TF_R(x0,x1,17) TF_R(x0,x1,29) TF_R(x0,x1,16) TF_R(x0,x1,24)
  x0 += ks2; x1 += k0 + 2u;
  TF_R(x0,x1,13) TF_R(x0,x1,15) TF_R(x0,x1,26) TF_R(x0,x1,6)
  x0 += k0;  x1 += k1 + 3u;
  TF_R(x0,x1,17) TF_R(x0,x1,29) TF_R(x0,x1,16) TF_R(x0,x1,24)
  x0 += k1;  x1 += ks2 + 4u;
  TF_R(x0,x1,13) TF_R(x0,x1,15) TF_R(x0,x1,26) TF_R(x0,x1,6)
  x0 += ks2; x1 += k0 + 5u;
  return {x0, x1};
}

constexpr TF2 NK0 = threefry2x32(0u, 1u, 0u, 0u);  // bin heads
constexpr TF2 NK1 = threefry2x32(0u, 1u, 0u, 1u);  // like heads
constexpr TF2 NK2 = threefry2x32(0u, 1u, 0u, 2u);  // mask heads

__device__ __forceinline__ unsigned short f2bf(float f) {
  unsigned u = __float_as_uint(f);
  return (unsigned short)((u + 0x7fffu + ((u >> 16) & 1u)) >> 16);
}

// ---------------- prep: fragment-linear packed bf16 weights in d_ws ----------------
// W1p frag f = nt*4+ks: elem (lane l, j): n = (f>>2)*16 + (l&15); k = (f&3)*32 + (l>>4)*8 + j
// Wallp frag g = nt*32+kt: same intra-frag mapping
__global__ void prep_kernel(const float* __restrict__ W1,
                            const float* __restrict__ Wnum, const float* __restrict__ Wcat,
                            const float* __restrict__ Wbin, const float* __restrict__ Wlike,
                            const float* __restrict__ Wmask,
                            const float* __restrict__ bnum, const float* __restrict__ bcat,
                            const float* __restrict__ bbin, const float* __restrict__ blike,
                            const float* __restrict__ bmask,
                            unsigned short* __restrict__ W1p,
                            unsigned short* __restrict__ Wallp,
                            float* __restrict__ ball) {
  int t = blockIdx.x * 256 + threadIdx.x;
  if (t < 16384) {
    int f = t >> 6, l = t & 63;
    int n = (f >> 2) * 16 + (l & 15);
    int kk0 = (f & 3) * 32 + (l >> 4) * 8;
    ushort8v p;
    #pragma unroll
    for (int j = 0; j < 8; ++j) p[j] = f2bf(W1[(size_t)(kk0 + j) * HIDD + n]);
    *(ushort8v*)(W1p + (size_t)t * 8) = p;
  } else if (t < 16384 + 40960) {
    int t2 = t - 16384;
    int g = t2 >> 6, l = t2 & 63;
    int nt = g >> 5, kt = g & 31;
    int n = nt * 16 + (l & 15);
    int kk0 = kt * 32 + (l >> 4) * 8;
    ushort8v p;
    #pragma unroll
    for (int j = 0; j < 8; ++j) {
      int kk = kk0 + j;
      float v = 0.f;
      if (n < 32)       v = Wnum [(size_t)kk * 32  + n];
      else if (n < 230) v = Wcat [(size_t)kk * 198 + (n - 32)];
      else if (n < 238) v = Wbin [(size_t)kk * 8   + (n - 230)];
      else if (n < 240) v = Wlike[(size_t)kk * 2   + (n - 238)];
      else if (n < 294) v = Wmask[(size_t)kk * 54  + (n - 240)];
      p[j] = f2bf(v);
    }
    *(ushort8v*)(Wallp + (size_t)t2 * 8) = p;
  } else if (t < 16384 + 40960 + 320) {
    int n = t - (16384 + 40960);
    float v = 0.f;
    if (n < 32)       v = bnum [n];
    else if (n < 230) v = bcat [n - 32];
    else if (n < 238) v = bbin [n - 230];
    else if (n < 240) v = blike[n - 238];
    else if (n < 294) v = bmask[n - 240];
    ball[n] = v;
  }
}

// ---------------- kernel A: h = relu(z@W1 + b1), fragment-tiled bf16 to d_ws ----------------
// 256 WGs x 1024 thr (16 waves): wave = (rh = w>>3: 32-row half, hs = w&7: 128-hc slice).
// Epilogue folded into the t-loop: live regs ~75 (no spill at 4 waves/SIMD).
// Grid 256 matches kernel B's grid -> h block b produced & consumed on the same XCD (L2-local).
// h tile layout (per 64-row x 128-hc tile, 16 KB): frag (ks,rt) at (ks*4+rt)*1024,
//   lane-linear 16 B per lane = B-side A-fragment image (zero-conflict ds_read_b128 in B).
__global__ __launch_bounds__(1024, 4) void h_kernel(
    const float* __restrict__ z, const float* __restrict__ b1,
    const unsigned short* __restrict__ W1p, unsigned char* __restrict__ hws) {
  const int tid  = threadIdx.x;
  const int lane = tid & 63;
  const int w    = tid >> 6;        // 0..15
  const int rh   = w >> 3;          // row half (32 rows)
  const int hs   = w & 7;           // hc slice (128 cols)
  const int l15  = lane & 15;
  const int l4   = lane >> 4;
  const int rb   = blockIdx.x * 64;

  // z B-frags for my 32 rows (rows rb + rh*32 + rt*16 + l15)
  bf16x8 zb[2][4];
  #pragma unroll
  for (int rt = 0; rt < 2; ++rt)
    #pragma unroll
    for (int ks = 0; ks < 4; ++ks) {
      const float* src = z + (size_t)(rb + rh * 32 + rt * 16 + l15) * LATD + ks * 32 + l4 * 8;
      f32x4 f0 = *(const f32x4*)src;
      f32x4 f1 = *(const f32x4*)(src + 4);
      bf16x8 p;
      p[0] = (__bf16)f0[0]; p[1] = (__bf16)f0[1]; p[2] = (__bf16)f0[2]; p[3] = (__bf16)f0[3];
      p[4] = (__bf16)f1[0]; p[5] = (__bf16)f1[1]; p[6] = (__bf16)f1[2]; p[7] = (__bf16)f1[3];
      zb[rt][ks] = p;
    }

  const size_t tile_base = ((size_t)blockIdx.x * 8 + hs) * 16384;

  #pragma unroll
  for (int t = 0; t < 8; ++t) {
    f32x4 a0 = {}, a1 = {};
    #pragma unroll
    for (int ks = 0; ks < 4; ++ks) {
      bf16x8 wA = *(const bf16x8*)(W1p + ((size_t)(hs * 8 + t) * 4 + ks) * 512 + lane * 8);
      a0 = __builtin_amdgcn_mfma_f32_16x16x32_bf16(wA, zb[0][ks], a0, 0, 0, 0);
      a1 = __builtin_amdgcn_mfma_f32_16x16x32_bf16(wA, zb[1][ks], a1, 0, 0, 0);
    }
    f32x4 bias = *(const f32x4*)(b1 + hs * 128 + t * 16 + l4 * 4);
    #pragma unroll
    for (int rt = 0; rt < 2; ++rt) {
      f32x4 a = rt ? a1 : a0;
      float v0 = fmaxf(a[0] + bias[0], 0.f);
      float v1 = fmaxf(a[1] + bias[1], 0.f);
      float v2 = fmaxf(a[2] + bias[2], 0.f);
      float v3 = fmaxf(a[3] + bias[3], 0.f);
      uint2v u;
      u[0] = (unsigned)f2bf(v0) | ((unsigned)f2bf(v1) << 16);
      u[1] = (unsigned)f2bf(v2) | ((unsigned)f2bf(v3) << 16);
      int rhalf = rh * 2 + rt;                        // r_loc>>4
      int byte = (((t >> 1) * 4 + rhalf) * 1024)      // frag (ks = t>>1, rt = rhalf)
               + l15 * 16
               + (((t & 1) * 2 + (l4 >> 1)) * 256)    // (hcl>>3)&3
               + ((l4 & 1) * 8);
      *(uint2v*)(hws + tile_base + byte) = u;
    }
  }
}

// ---------------- kernel B: out = h @ Wall + bias, gumbel heads, scatter ----------------
// 256 WGs x 640 thr (10 waves). Wave = 64 rows x 32 out cols, full K=1024 (no reduction).
// 3-buffer LDS ring staged via global_load_lds; counted vmcnt(2) + raw s_barrier (never
// vmcnt(0) mid-loop); wb loads pinned BEFORE stage-issue so their FIFO vmcnt wait doesn't
// drain the newest stage. One barrier per chunk.
__global__ __launch_bounds__(640, 2) void out_kernel(
    const unsigned char* __restrict__ hws, const unsigned short* __restrict__ Wallp,
    const float* __restrict__ ball, float* __restrict__ out) {
  __shared__ __align__(16) unsigned char smem[82176];  // ring 3x16K (staging) / outs 64x321 f32
  float* outs = (float*)smem;

  const int tid  = threadIdx.x;
  const int lane = tid & 63;
  const int wv   = tid >> 6;        // 0..9
  const int l15  = lane & 15;
  const int l4   = lane >> 4;
  const int rb   = blockIdx.x * 64;
  const int cb   = wv * 32;
  const size_t hblk = (size_t)blockIdx.x * (8 * 16384);
  const bool stager = (wv < 8);
  const int s0 = wv * 2;

  f32x4 acc[4][2] = {};

#define STAGE(CHUNK, SEG, BUFI)                                                              \
  __builtin_amdgcn_global_load_lds(                                                         \
      (const __attribute__((address_space(1))) unsigned int*)(hws + hblk +                   \
          (size_t)(CHUNK) * 16384 + (SEG) * 1024 + lane * 16),                               \
      (__attribute__((address_space(3))) unsigned int*)(smem + (BUFI) * 16384 + (SEG) * 1024),\
      16, 0, 0)

  // prologue: stage chunks 0 and 1
  if (stager) {
    STAGE(0, s0, 0); STAGE(0, s0 + 1, 0);
    STAGE(1, s0, 1); STAGE(1, s0 + 1, 1);
  }

  #pragma unroll
  for (int c = 0; c < 8; ++c) {
    // counted wait: my stage(c) loads landed (S(c+1) stays in flight); publish via barrier
    if (c < 7) asm volatile("s_waitcnt vmcnt(2)" ::: "memory");
    else       asm volatile("s_waitcnt vmcnt(0)" ::: "memory");
    asm volatile("s_waitcnt lgkmcnt(0)" ::: "memory");
    __builtin_amdgcn_s_barrier();
    asm volatile("" ::: "memory");

    // weights for this chunk (issued FIRST so their vmcnt wait precedes stage(c+2) in FIFO)
    bf16x8 wb[2][4];
    #pragma unroll
    for (int ct = 0; ct < 2; ++ct)
      #pragma unroll
      for (int ks = 0; ks < 4; ++ks)
        wb[ct][ks] = *(const bf16x8*)(Wallp +
            ((size_t)((wv * 2 + ct) * 32 + c * 4 + ks) * 64 + lane) * 8);
    asm volatile("" ::: "memory");   // pin wb above the stage-issue

    if (c + 2 < 8 && stager) {
      STAGE(c + 2, s0, (c + 2) % 3);
      STAGE(c + 2, s0 + 1, (c + 2) % 3);
    }

    const unsigned char* buf = smem + (c % 3) * 16384;
    #pragma unroll
    for (int ks = 0; ks < 4; ++ks) {
      bf16x8 ha[4];
      #pragma unroll
      for (int rt = 0; rt < 4; ++rt)
        ha[rt] = *(const bf16x8*)(buf + (ks * 4 + rt) * 1024 + lane * 16);
      #pragma unroll
      for (int rt = 0; rt < 4; ++rt)
        #pragma unroll
        for (int ct = 0; ct < 2; ++ct)
          acc[rt][ct] = __builtin_amdgcn_mfma_f32_16x16x32_bf16(ha[rt], wb[ct][ks], acc[rt][ct], 0, 0, 0);
    }
  }
#undef STAGE

  __syncthreads();   // all chunk reads done; LDS becomes outs

  // ---- acc -> outs[64][321] (+fused bias); each wave owns its 32 cols ----
  float bias2[2];
  #pragma unroll
  for (int ct = 0; ct < 2; ++ct) bias2[ct] = ball[cb + ct * 16 + l15];
  #pragma unroll
  for (int rt = 0; rt < 4; ++rt)
    #pragma unroll
    for (int ct = 0; ct < 2; ++ct)
      #pragma unroll
      for (int j = 0; j < 4; ++j)
        outs[(rt * 16 + l4 * 4 + j) * 321 + cb + ct * 16 + l15] = acc[rt][ct][j] + bias2[ct];
  __syncthreads();

  // ---- write num + cat blocks (row-major [B, card] chunks, contiguous float4, NT) ----
  {
    constexpr int cards[13] = {32,10,20,15,8,30,12,5,25,6,40,18,9};
    constexpr int cbase[13] = {0,32,42,62,77,85,115,127,132,157,163,203,221};
    #pragma unroll
    for (int blk = 0; blk < 13; ++blk) {
      const int card = cards[blk];
      const int cbs  = cbase[blk];
      float* gout = out + (size_t)B_ROWS * cbs + (size_t)rb * card;
      for (int v = tid; v < card * 16; v += 640) {
        int gg = v * 4;
        f32x4v vbuf;
        #pragma unroll
        for (int e = 0; e < 4; ++e) {
          int ge = gg + e;
          int brow = ge / card;
          int j = ge - brow * card;
          vbuf[e] = outs[brow * 321 + cbs + j];
        }
        __builtin_nontemporal_store(vbuf, (f32x4v*)(gout + gg));
      }
    }
  }

  // ---- gumbel-sigmoid heads: cols 230..293, out[B*c + b] ----
  if (tid < 512) {
    int c = 230 + (tid >> 3);
    unsigned ka, kb; int Nh, head;
    if (c < 238)      { ka = NK0.a; kb = NK0.b; Nh = 8;  head = c - 230; }
    else if (c < 240) { ka = NK1.a; kb = NK1.b; Nh = 2;  head = c - 238; }
    else              { ka = NK2.a; kb = NK2.b; Nh = 54; head = c - 240; }
    #pragma unroll
    for (int q = 0; q < 2; ++q) {
      int rq = (tid & 7) * 4 + q * 32;
      f32x4v vbuf;
      #pragma unroll
      for (int e = 0; e < 4; ++e) {
        int rl = rq + e;
        float x = outs[rl * 321 + c];
        unsigned j = (unsigned)((rb + rl) * Nh + head);
        TF2 t = threefry2x32(ka, kb, 0u, j);
        unsigned bits = t.a ^ t.b;
        float u  = __uint_as_float((bits >> 9) | 0x3f800000u) - 1.0f;
        float gn = -logf(-logf(u + 1e-20f) + 1e-20f);
        vbuf[e] = 1.0f / (1.0f + expf(-(x + gn)));
      }
      __builtin_nontemporal_store(vbuf, (f32x4v*)(out + (size_t)B_ROWS * c + rb + rq));
    }
  }
}

// ---------------- fallback fused decoder (round-2, proven 34 us) ----------------
__global__ __launch_bounds__(512, 2) void decoder_kernel(
    const float* __restrict__ z, const float* __restrict__ b1,
    const unsigned short* __restrict__ W1p, const unsigned short* __restrict__ Wallp,
    const float* __restrict__ ball, float* __restrict__ out) {
  __shared__ __align__(16) unsigned char smem[82176];
  unsigned short* zs  = (unsigned short*)smem;
  unsigned short* hs0 = (unsigned short*)(smem + 17408);
  unsigned short* hs1 = (unsigned short*)(smem + 34816);
  float* outs = (float*)smem;

  const int tid  = threadIdx.x;
  const int lane = tid & 63;
  const int wv   = tid >> 6;
  const int wc   = wv & 3;
  const int wk   = wv >> 2;
  const int l15  = lane & 15;
  const int l4   = lane >> 4;
  const int r0   = blockIdx.x * 64;

  #pragma unroll
  for (int it = 0; it < 2; ++it) {
    int ch  = tid + it * 512;
    int row = ch >> 4;
    int k0  = (ch & 15) * 8;
    const float* src = z + (size_t)(r0 + row) * LATD + k0;
    f32x4 f0 = *(const f32x4*)src;
    f32x4 f1 = *(const f32x4*)(src + 4);
    ushort8v p;
    p[0] = f2bf(f0[0]); p[1] = f2bf(f0[1]); p[2] = f2bf(f0[2]); p[3] = f2bf(f0[3]);
    p[4] = f2bf(f1[0]); p[5] = f2bf(f1[1]); p[6] = f2bf(f1[2]); p[7] = f2bf(f1[3]);
    *(ushort8v*)(zs + row * 136 + k0) = p;
  }

  float bb[4][2];
  #pragma unroll
  for (int i = 0; i < 4; ++i)
    #pragma unroll
    for (int ct = 0; ct < 2; ++ct)
      bb[i][ct] = b1[(wk * 4 + i) * 128 + wc * 32 + ct * 16 + l15];
  float bias2[5];
  #pragma unroll
  for (int ct = 0; ct < 5; ++ct) bias2[ct] = ball[wc * 80 + ct * 16 + l15];

  unsigned short* hw = wk ? hs1 : hs0;
  f32x4 acc2[4][5] = {};
  __syncthreads();

  #pragma unroll
  for (int i = 0; i < 4; ++i) {
    const int c = wk * 4 + i;
    bf16x8 wb1[2][4];
    #pragma unroll
    for (int ct = 0; ct < 2; ++ct)
      #pragma unroll
      for (int ks = 0; ks < 4; ++ks)
        wb1[ct][ks] = *(const bf16x8*)(W1p + (size_t)(((c * 8 + wc * 2 + ct) * 4 + ks) * 64 + lane) * 8);
    f32x4 acc1[4][2] = {};
    #pragma unroll
    for (int ks = 0; ks < 4; ++ks) {
      bf16x8 za[4];
      #pragma unroll
      for (int rt = 0; rt < 4; ++rt)
        za[rt] = *(const bf16x8*)(zs + (rt * 16 + l15) * 136 + ks * 32 + l4 * 8);
      #pragma unroll
      for (int rt = 0; rt < 4; ++rt)
        #pragma unroll
        for (int ct = 0; ct < 2; ++ct)
          acc1[rt][ct] = __builtin_amdgcn_mfma_f32_16x16x32_bf16(za[rt], wb1[ct][ks], acc1[rt][ct], 0, 0, 0);
    }
    bf16x8 wb2[5][4];
    #pragma unroll
    for (int ct = 0; ct < 5; ++ct)
      #pragma unroll
      for (int ks = 0; ks < 4; ++ks)
        wb2[ct][ks] = *(const bf16x8*)(Wallp + (size_t)(((wc * 5 + ct) * 32 + c * 4 + ks) * 64 + lane) * 8);
    __syncthreads();
    #pragma unroll
    for (int rt = 0; rt < 4; ++rt)
      #pragma unroll
      for (int ct = 0; ct < 2; ++ct)
        #pragma unroll
        for (int j = 0; j < 4; ++j) {
          float v = fmaxf(acc1[rt][ct][j] + bb[i][ct], 0.f);
          hw[(rt * 16 + l4 * 4 + j) * 136 + wc * 32 + ct * 16 + l15] = f2bf(v);
        }
    __syncthreads();
    #pragma unroll
    for (int ks = 0; ks < 4; ++ks) {
      bf16x8 ha[4];
      #pragma unroll
      for (int rt = 0; rt < 4; ++rt)
        ha[rt] = *(const bf16x8*)(hw + (rt * 16 + l15) * 136 + ks * 32 + l4 * 8);
      #pragma unroll
      for (int rt = 0; rt < 4; ++rt)
        #pragma unroll
        for (int ct = 0; ct < 5; ++ct)
          acc2[rt][ct] = __builtin_amdgcn_mfma_f32_16x16x32_bf16(ha[rt], wb2[ct][ks], acc2[rt][ct], 0, 0, 0);
    }
  }
  __syncthreads();

  if (wk == 0) {
    #pragma unroll
    for (int rt = 0; rt < 4; ++rt)
      #pragma unroll
      for (int ct = 0; ct < 5; ++ct)
        #pragma unroll
        for (int j = 0; j < 4; ++j)
          outs[(rt * 16 + l4 * 4 + j) * 321 + wc * 80 + ct * 16 + l15] = acc2[rt][ct][j] + bias2[ct];
  }
  __syncthreads();
  if (wk == 1) {
    #pragma unroll
    for (int rt = 0; rt < 4; ++rt)
      #pragma unroll
      for (int ct = 0; ct < 5; ++ct)
        #pragma unroll
        for (int j = 0; j < 4; ++j)
          outs[(rt * 16 + l4 * 4 + j) * 321 + wc * 80 + ct * 16 + l15] += acc2[rt][ct][j];
  }
  __syncthreads();

  {
    constexpr int cards[13] = {32,10,20,15,8,30,12,5,25,6,40,18,9};
    constexpr int cbase[13] = {0,32,42,62,77,85,115,127,132,157,163,203,221};
    #pragma unroll
    for (int blk = 0; blk < 13; ++blk) {
      const int card = cards[blk];
      const int cbs  = cbase[blk];
      float* gout = out + (size_t)B_ROWS * cbs + (size_t)r0 * card;
      for (int v = tid; v < card * 16; v += 512) {
        int gg = v * 4;
        f32x4v vbuf;
        #pragma unroll
        for (int e = 0; e < 4; ++e) {
          int ge = gg + e;
          int brow = ge / card;
          int j = ge - brow * card;
          vbuf[e] = outs[brow * 321 + cbs + j];
        }
        *(f32x4v*)(gout + gg) = vbuf;
      }
    }
  }
  {
    int c = 230 + (tid >> 3);
    unsigned ka, kb; int Nh, head;
    if (c < 238)      { ka = NK0.a; kb = NK0.b; Nh = 8;  head = c - 230; }
    else if (c < 240) { ka = NK1.a; kb = NK1.b; Nh = 2;  head = c - 238; }
    else              { ka = NK2.a; kb = NK2.b; Nh = 54; head = c - 240; }
    #pragma unroll
    for (int q = 0; q < 2; ++q) {
      int rq = (tid & 7) * 4 + q * 32;
      f32x4v vbuf;
      #pragma unroll
      for (int e = 0; e < 4; ++e) {
        int rl = rq + e;
        float x = outs[rl * 321 + c];
        unsigned j = (unsigned)((r0 + rl) * Nh + head);
        TF2 t = threefry2x32(ka, kb, 0u, j);
        unsigned bits = t.a ^ t.b;
        float u  = __uint_as_float((bits >> 9) | 0x3f800000u) - 1.0f;
        float gn = -logf(-logf(u + 1e-20f) + 1e-20f);
        vbuf[e] = 1.0f / (1.0f + expf(-(x + gn)));
      }
      *(f32x4v*)(out + (size_t)B_ROWS * c + r0 + rq) = vbuf;
    }
  }
}

// ---------------- launch ----------------
extern "C" void kernel_launch(void* const* d_in, const int* in_sizes, int n_in,
                              void* d_out, int out_size, void* d_ws, size_t ws_size,
                              hipStream_t stream) {
  const float* z     = (const float*)d_in[0];
  const float* W1    = (const float*)d_in[1];
  const float* b1    = (const float*)d_in[2];
  const float* Wnum  = (const float*)d_in[3];
  const float* bnum  = (const float*)d_in[4];
  const float* Wcat  = (const float*)d_in[5];
  const float* bcat  = (const float*)d_in[6];
  const float* Wbin  = (const float*)d_in[7];
  const float* bbin  = (const float*)d_in[8];
  const float* Wlike = (const float*)d_in[9];
  const float* blike = (const float*)d_in[10];
  const float* Wmask = (const float*)d_in[11];
  const float* bmask = (const float*)d_in[12];

  unsigned short* W1p   = (unsigned short*)d_ws;            // 131072 bf16 = 256 KB
  unsigned short* Wallp = W1p + 131072;                     // 327680 bf16 = 640 KB
  float*          ball  = (float*)(Wallp + 327680);         // 320 f32
  const size_t HOFF = 1u << 20;                             // h at +1 MB
  unsigned char*  hws   = (unsigned char*)d_ws + HOFF;      // 32 MB fragment-tiled h

  const int total = 16384 + 40960 + 320;
  prep_kernel<<<(total + 255) / 256, 256, 0, stream>>>(
      W1, Wnum, Wcat, Wbin, Wlike, Wmask, bnum, bcat, bbin, blike, bmask,
      W1p, Wallp, ball);

  if (ws_size >= HOFF + (size_t)32 * 1024 * 1024) {
    h_kernel<<<256, 1024, 0, stream>>>(z, b1, W1p, hws);
    out_kernel<<<256, 640, 0, stream>>>(hws, Wallp, ball, (float*)d_out);
  } else {
    decoder_kernel<<<B_ROWS / 64, 512, 0, stream>>>(
        z, b1, W1p, Wallp, ball, (float*)d_out);
  }
}

// Round 7
// 29.498 us; speedup vs baseline: 1.8092x; 1.6662x over previous
//
#include <hip/hip_runtime.h>
#include <stdint.h>

// ---------------- problem constants ----------------
#define B_ROWS 16384
#define LATD   128
#define HIDD   1024

typedef __bf16 bf16x8 __attribute__((ext_vector_type(8)));
typedef float  f32x4  __attribute__((ext_vector_type(4)));
typedef float  f32x4v __attribute__((ext_vector_type(4)));
typedef unsigned short ushort8v __attribute__((ext_vector_type(8)));
typedef unsigned int   uint2v   __attribute__((ext_vector_type(2)));

// ---------------- asm helpers: unsinkable weight loads + counted waits ----------------
template<int N> __device__ __forceinline__ void waitv() {
  asm volatile("s_waitcnt vmcnt(%0)" :: "i"(N) : "memory");
  __builtin_amdgcn_sched_barrier(0);   // rule-18: no MFMA may hoist above the wait
}
__device__ __forceinline__ void gl16(bf16x8& r, const unsigned short* p) {
  asm volatile("global_load_dwordx4 %0, %1, off" : "=v"(r) : "v"(p));
}
template<int OFF> __device__ __forceinline__ void gl16o(bf16x8& r, const unsigned short* p) {
  asm volatile("global_load_dwordx4 %0, %1, off offset:%2" : "=v"(r) : "v"(p), "i"(OFF));
}
// barrier that drains LDS ops only — asm weight loads stay in flight
#define LGKM_BARRIER() do {                                        \
    asm volatile("s_waitcnt lgkmcnt(0)" ::: "memory");             \
    __builtin_amdgcn_s_barrier();                                  \
    asm volatile("" ::: "memory");                                 \
  } while (0)

// ---------------- threefry2x32 (matches JAX, partitionable default) ----------------
struct TF2 { unsigned int a, b; };

#define TF_R(x0,x1,r) { x0 += x1; x1 = ((x1 << (r)) | (x1 >> (32 - (r)))); x1 ^= x0; }

__host__ __device__ constexpr TF2 threefry2x32(unsigned k0, unsigned k1, unsigned c0, unsigned c1) {
  unsigned ks2 = k0 ^ k1 ^ 0x1BD11BDAu;
  unsigned x0 = c0 + k0, x1 = c1 + k1;
  TF_R(x0,x1,13) TF_R(x0,x1,15) TF_R(x0,x1,26) TF_R(x0,x1,6)
  x0 += k1;  x1 += ks2 + 1u;
  TF_R(x0,x1,17) TF_R(x0,x1,29) TF_R(x0,x1,16) TF_R(x0,x1,24)
  x0 += ks2; x1 += k0 + 2u;
  TF_R(x0,x1,13) TF_R(x0,x1,15) TF_R(x0,x1,26) TF_R(x0,x1,6)
  x0 += k0;  x1 += k1 + 3u;
  TF_R(x0,x1,17) TF_R(x0,x1,29) TF_R(x0,x1,16) TF_R(x0,x1,24)
  x0 += k1;  x1 += ks2 + 4u;
  TF_R(x0,x1,13) TF_R(x0,x1,15) TF_R(x0,x1,26) TF_R(x0,x1,6)
  x0 += ks2; x1 += k0 + 5u;
  return {x0, x1};
}

constexpr TF2 NK0 = threefry2x32(0u, 1u, 0u, 0u);  // bin heads
constexpr TF2 NK1 = threefry2x32(0u, 1u, 0u, 1u);  // like heads
constexpr TF2 NK2 = threefry2x32(0u, 1u, 0u, 2u);  // mask heads

__device__ __forceinline__ unsigned short f2bf(float f) {
  unsigned u = __float_as_uint(f);
  return (unsigned short)((u + 0x7fffu + ((u >> 16) & 1u)) >> 16);
}

// ---------------- prep: fragment-linear packed bf16 weights in d_ws (UNCHANGED, proven) ----------------
// W1p frag f = nt*4+ks: elem (lane l, j): n = (f>>2)*16 + (l&15); k = (f&3)*32 + (l>>4)*8 + j
// Wallp frag g = nt*32+kt: same intra-frag mapping
__global__ void prep_kernel(const float* __restrict__ W1,
                            const float* __restrict__ Wnum, const float* __restrict__ Wcat,
                            const float* __restrict__ Wbin, const float* __restrict__ Wlike,
                            const float* __restrict__ Wmask,
                            const float* __restrict__ bnum, const float* __restrict__ bcat,
                            const float* __restrict__ bbin, const float* __restrict__ blike,
                            const float* __restrict__ bmask,
                            unsigned short* __restrict__ W1p,
                            unsigned short* __restrict__ Wallp,
                            float* __restrict__ ball) {
  int t = blockIdx.x * 256 + threadIdx.x;
  if (t < 16384) {
    int f = t >> 6, l = t & 63;
    int n = (f >> 2) * 16 + (l & 15);
    int kk0 = (f & 3) * 32 + (l >> 4) * 8;
    ushort8v p;
    #pragma unroll
    for (int j = 0; j < 8; ++j) p[j] = f2bf(W1[(size_t)(kk0 + j) * HIDD + n]);
    *(ushort8v*)(W1p + (size_t)t * 8) = p;
  } else if (t < 16384 + 40960) {
    int t2 = t - 16384;
    int g = t2 >> 6, l = t2 & 63;
    int nt = g >> 5, kt = g & 31;
    int n = nt * 16 + (l & 15);
    int kk0 = kt * 32 + (l >> 4) * 8;
    ushort8v p;
    #pragma unroll
    for (int j = 0; j < 8; ++j) {
      int kk = kk0 + j;
      float v = 0.f;
      if (n < 32)       v = Wnum [(size_t)kk * 32  + n];
      else if (n < 230) v = Wcat [(size_t)kk * 198 + (n - 32)];
      else if (n < 238) v = Wbin [(size_t)kk * 8   + (n - 230)];
      else if (n < 240) v = Wlike[(size_t)kk * 2   + (n - 238)];
      else if (n < 294) v = Wmask[(size_t)kk * 54  + (n - 240)];
      p[j] = f2bf(v);
    }
    *(ushort8v*)(Wallp + (size_t)t2 * 8) = p;
  } else if (t < 16384 + 40960 + 320) {
    int n = t - (16384 + 40960);
    float v = 0.f;
    if (n < 32)       v = bnum [n];
    else if (n < 230) v = bcat [n - 32];
    else if (n < 238) v = bbin [n - 230];
    else if (n < 240) v = blike[n - 238];
    else if (n < 294) v = bmask[n - 240];
    ball[n] = v;
  }
}

// ---------------- two-phase fused decoder core ----------------
// Phase 1: wave w computes h chunk w (128 hid-cols, 64 rows) via swapped MFMA
//   (mfma(W1-colfrag, z-rowfrag) -> lane holds 4 consecutive hid-cols per z-row),
//   writes fragment-linear h tile (the GEMM2 A-frag image) to LDS.
//   Weight stream: contiguous 32 KB per wave, ring-2 groups of 4 KB, wait vmcnt(4).
// Barrier: lgkm-only; phase-2 weight groups 0..3 pre-issued BEFORE it (vmcnt never 0).
// Phase 2: wave w owns G*16 out cols (G=3 for w<4, else 2), full K=1024, NO barriers.
//   32 groups (kt = 0..31): wait vmcnt(3G..0 tail), 4 ds_read_b128 + 4G MFMA, issue g+4.
template<int G>
__device__ __forceinline__ void run_phases(
    const int w, const int lane, const int l15, const int l4, const int nt0,
    const unsigned short* __restrict__ W1p, const unsigned short* __restrict__ Wallp,
    const float* __restrict__ b1,
    unsigned char* smem, f32x4 (&acc)[4][3]) {

  unsigned short* zs = (unsigned short*)smem;          // [64][136] bf16
  unsigned char* hbase  = smem + 17408;                // 8 x 16 KB h tiles
  unsigned char* mytile = hbase + w * 16384;

  // ---- ALL plain global loads happen before the asm stream starts ----
  f32x4 hb1[8];
  #pragma unroll
  for (int ct = 0; ct < 8; ++ct)
    hb1[ct] = *(const f32x4*)(b1 + w * 128 + ct * 16 + l4 * 4);

  // z B-fragments from LDS (broadcast-friendly; 2-way bank alias = free)
  bf16x8 za[4][4];
  #pragma unroll
  for (int rt = 0; rt < 4; ++rt)
    #pragma unroll
    for (int ks = 0; ks < 4; ++ks)
      za[rt][ks] = *(const bf16x8*)(zs + (rt * 16 + l15) * 136 + ks * 32 + l4 * 8);

  // ---- phase-1 weight ring: wave stream = W1p + w*32KB, group ct = 4 KB ----
  bf16x8 wq1[2][4];
  const unsigned short* w1b = W1p + (size_t)w * 16384 + lane * 8;
  #pragma unroll
  for (int ct = 0; ct < 2; ++ct) {
    const unsigned short* p = w1b + ct * 2048;
    gl16o<0>(wq1[ct][0], p); gl16o<1024>(wq1[ct][1], p);
    gl16o<2048>(wq1[ct][2], p); gl16o<3072>(wq1[ct][3], p);
  }

  bf16x8 wq2[4][G];   // phase-2 ring (4 groups deep)
  const unsigned short* w2b = Wallp + lane * 8;

  // ---- phase 1 ----
  #pragma unroll
  for (int ct = 0; ct < 8; ++ct) {
    if (ct < 7) waitv<4>();          // group ct landed; ct+1 in flight
    else        waitv<G * 4>();      // g7 landed; PH2 groups 0..3 in flight
    f32x4 a[4] = {};
    #pragma unroll
    for (int ks = 0; ks < 4; ++ks)
      #pragma unroll
      for (int rt = 0; rt < 4; ++rt)
        a[rt] = __builtin_amdgcn_mfma_f32_16x16x32_bf16(wq1[ct & 1][ks], za[rt][ks], a[rt], 0, 0, 0);
    // pack (+bias, relu) -> fragment-linear h tile (quad of hid-cols per lane)
    #pragma unroll
    for (int rt = 0; rt < 4; ++rt) {
      float v0 = fmaxf(a[rt][0] + hb1[ct][0], 0.f);
      float v1 = fmaxf(a[rt][1] + hb1[ct][1], 0.f);
      float v2 = fmaxf(a[rt][2] + hb1[ct][2], 0.f);
      float v3 = fmaxf(a[rt][3] + hb1[ct][3], 0.f);
      uint2v u;
      u[0] = (unsigned)f2bf(v0) | ((unsigned)f2bf(v1) << 16);
      u[1] = (unsigned)f2bf(v2) | ((unsigned)f2bf(v3) << 16);
      const int byte = ((ct >> 1) * 4 + rt) * 1024
                     + ((ct & 1) * 2 + (l4 >> 1)) * 256
                     + l15 * 16 + (l4 & 1) * 8;
      *(uint2v*)(mytile + byte) = u;
    }
    if (ct < 6) {                    // refill ring slot just consumed
      const unsigned short* p = w1b + (ct + 2) * 2048;
      gl16o<0>(wq1[ct & 1][0], p); gl16o<1024>(wq1[ct & 1][1], p);
      gl16o<2048>(wq1[ct & 1][2], p); gl16o<3072>(wq1[ct & 1][3], p);
    } else if (ct == 6) {            // pre-issue phase-2 groups 0..3 (cross-barrier)
      #pragma unroll
      for (int g = 0; g < 4; ++g)
        #pragma unroll
        for (int cc = 0; cc < G; ++cc)
          gl16(wq2[g][cc], w2b + (size_t)((nt0 + cc) * 32 + g) * 512);
    }
  }

  LGKM_BARRIER();    // h visible to all waves; weight prefetches stay in flight

  // ---- phase 2 ----
  #pragma unroll
  for (int rt = 0; rt < 4; ++rt)
    #pragma unroll
    for (int ct = 0; ct < 3; ++ct)
      acc[rt][ct] = (f32x4){0.f, 0.f, 0.f, 0.f};

  #pragma unroll
  for (int g = 0; g < 32; ++g) {     // group g <-> kt = g (c = g>>2, ksl = g&3)
    if (g < 29)      waitv<G * 3>(); // group g landed; 3 groups still in flight
    else if (g == 29) waitv<G * 2>();
    else if (g == 30) waitv<G>();
    else              waitv<0>();
    const unsigned char* hc = hbase + (g >> 2) * 16384 + (g & 3) * 4096 + lane * 16;
    #pragma unroll
    for (int rt = 0; rt < 4; ++rt) {
      bf16x8 ha = *(const bf16x8*)(hc + rt * 1024);   // lane-linear, conflict-free
      #pragma unroll
      for (int ct = 0; ct < G; ++ct)
        acc[rt][ct] = __builtin_amdgcn_mfma_f32_16x16x32_bf16(ha, wq2[g & 3][ct], acc[rt][ct], 0, 0, 0);
    }
    if (g + 4 < 32) {                // refill slot just consumed
      #pragma unroll
      for (int cc = 0; cc < G; ++cc)
        gl16(wq2[g & 3][cc], w2b + (size_t)((nt0 + cc) * 32 + (g + 4)) * 512);
    }
  }
}

// ---------------- main kernel: 256 WGs x 512 thr (8 waves), 64 rows/WG ----------------
// LDS: zs [64][136] bf16 (17408 B) | h 8 x 16384 B = 131072 B -> 148480 B total.
// Epilogue overlays outs[64][321] f32 (82176 B) after a full __syncthreads.
__global__ __launch_bounds__(512, 2) void decoder_kernel(
    const float* __restrict__ z, const float* __restrict__ b1,
    const unsigned short* __restrict__ W1p, const unsigned short* __restrict__ Wallp,
    const float* __restrict__ ball, float* __restrict__ out) {
  __shared__ __align__(16) unsigned char smem[148480];
  unsigned short* zs = (unsigned short*)smem;
  float* outs = (float*)smem;

  const int tid  = threadIdx.x;
  const int lane = tid & 63;
  const int w    = tid >> 6;        // 0..7
  const int l15  = lane & 15;
  const int l4   = lane >> 4;
  const int r0   = blockIdx.x * 64;

  // ---- stage z tile -> LDS bf16 (NT: streamed once, keep L2 for weights) ----
  #pragma unroll
  for (int it = 0; it < 2; ++it) {
    int ch  = tid + it * 512;       // 0..1023
    int row = ch >> 4;
    int k0  = (ch & 15) * 8;
    const float* src = z + (size_t)(r0 + row) * LATD + k0;
    f32x4v f0 = __builtin_nontemporal_load((const f32x4v*)src);
    f32x4v f1 = __builtin_nontemporal_load((const f32x4v*)(src + 4));
    ushort8v p;
    p[0] = f2bf(f0[0]); p[1] = f2bf(f0[1]); p[2] = f2bf(f0[2]); p[3] = f2bf(f0[3]);
    p[4] = f2bf(f1[0]); p[5] = f2bf(f1[1]); p[6] = f2bf(f1[2]); p[7] = f2bf(f1[3]);
    *(ushort8v*)(zs + row * 136 + k0) = p;
  }
  __syncthreads();   // full drain OK: no asm loads issued yet

  // col ownership: waves 0-3 -> 48 cols, waves 4-7 -> 32 cols (320 total)
  const int cb  = (w < 4) ? w * 48 : 192 + (w - 4) * 32;
  const int nt0 = (w < 4) ? w * 3  : 12 + (w - 4) * 2;
  const int myG = (w < 4) ? 3 : 2;

  f32x4 acc[4][3];
  if (w < 4) run_phases<3>(w, lane, l15, l4, nt0, W1p, Wallp, b1, smem, acc);
  else       run_phases<2>(w, lane, l15, l4, nt0, W1p, Wallp, b1, smem, acc);

  __syncthreads();   // all h reads done everywhere; LDS becomes outs

  // ---- acc -> outs[64][321] (+fused bias); full-K cols => no reduction ----
  #pragma unroll
  for (int ct = 0; ct < 3; ++ct) {
    if (ct < myG) {
      float b2 = ball[cb + ct * 16 + l15];
      #pragma unroll
      for (int rt = 0; rt < 4; ++rt)
        #pragma unroll
        for (int j = 0; j < 4; ++j)
          outs[(rt * 16 + l4 * 4 + j) * 321 + cb + ct * 16 + l15] = acc[rt][ct][j] + b2;
    }
  }
  __syncthreads();

  // ---- write num + cat blocks (row-major [B, card] chunks, contiguous float4, NT) ----
  {
    constexpr int cards[13] = {32,10,20,15,8,30,12,5,25,6,40,18,9};
    constexpr int cbase[13] = {0,32,42,62,77,85,115,127,132,157,163,203,221};
    #pragma unroll
    for (int blk = 0; blk < 13; ++blk) {
      const int card = cards[blk];
      const int cbs  = cbase[blk];
      float* gout = out + (size_t)B_ROWS * cbs + (size_t)r0 * card;
      for (int v = tid; v < card * 16; v += 512) {
        int gg = v * 4;
        f32x4v vbuf;
        #pragma unroll
        for (int e = 0; e < 4; ++e) {
          int ge = gg + e;
          int brow = ge / card;          // compile-time card -> magic mul
          int j = ge - brow * card;
          vbuf[e] = outs[brow * 321 + cbs + j];
        }
        __builtin_nontemporal_store(vbuf, (f32x4v*)(gout + gg));
      }
    }
  }

  // ---- gumbel-sigmoid heads: cols 230..293, out[B*c + b] ----
  {
    int c = 230 + (tid >> 3);
    unsigned ka, kb; int Nh, head;
    if (c < 238)      { ka = NK0.a; kb = NK0.b; Nh = 8;  head = c - 230; }
    else if (c < 240) { ka = NK1.a; kb = NK1.b; Nh = 2;  head = c - 238; }
    else              { ka = NK2.a; kb = NK2.b; Nh = 54; head = c - 240; }
    #pragma unroll
    for (int q = 0; q < 2; ++q) {
      int rq = (tid & 7) * 4 + q * 32;
      f32x4v vbuf;
      #pragma unroll
      for (int e = 0; e < 4; ++e) {
        int rl = rq + e;
        float x = outs[rl * 321 + c];
        unsigned j = (unsigned)((r0 + rl) * Nh + head);
        TF2 t = threefry2x32(ka, kb, 0u, j);
        unsigned bits = t.a ^ t.b;
        float u  = __uint_as_float((bits >> 9) | 0x3f800000u) - 1.0f;
        float gn = -logf(-logf(u + 1e-20f) + 1e-20f);
        vbuf[e] = 1.0f / (1.0f + expf(-(x + gn)));
      }
      __builtin_nontemporal_store(vbuf, (f32x4v*)(out + (size_t)B_ROWS * c + r0 + rq));
    }
  }
}

// ---------------- launch ----------------
extern "C" void kernel_launch(void* const* d_in, const int* in_sizes, int n_in,
                              void* d_out, int out_size, void* d_ws, size_t ws_size,
                              hipStream_t stream) {
  const float* z     = (const float*)d_in[0];
  const float* W1    = (const float*)d_in[1];
  const float* b1    = (const float*)d_in[2];
  const float* Wnum  = (const float*)d_in[3];
  const float* bnum  = (const float*)d_in[4];
  const float* Wcat  = (const float*)d_in[5];
  const float* bcat  = (const float*)d_in[6];
  const float* Wbin  = (const float*)d_in[7];
  const float* bbin  = (const float*)d_in[8];
  const float* Wlike = (const float*)d_in[9];
  const float* blike = (const float*)d_in[10];
  const float* Wmask = (const float*)d_in[11];
  const float* bmask = (const float*)d_in[12];

  unsigned short* W1p   = (unsigned short*)d_ws;            // 131072 bf16 = 256 KB
  unsigned short* Wallp = W1p + 131072;                     // 327680 bf16 = 640 KB
  float*          ball  = (float*)(Wallp + 327680);         // 320 f32

  const int total = 16384 + 40960 + 320;
  prep_kernel<<<(total + 255) / 256, 256, 0, stream>>>(
      W1, Wnum, Wcat, Wbin, Wlike, Wmask, bnum, bcat, bbin, blike, bmask,
      W1p, Wallp, ball);

  decoder_kernel<<<B_ROWS / 64, 512, 0, stream>>>(
      z, b1, W1p, Wallp, ball, (float*)d_out);
}